// Round 11
// baseline (1821.431 us; speedup 1.0000x reference)
//
#include <hip/hip_runtime.h>

// GraphLSTM-VAE on MI355X — round 15: TRUE weight residency via de-invariant ws.
// Root cause of r9-r11 failures found: ws was `const __restrict__` -> weight
// loads are invariant -> LLVM remats them across barriers, defeating both
// residency and asm pins. Fix: ws passed NON-const/non-restrict to lstm_main;
// barriers then fence ws -> pre-loop bw1 loads MUST stay register-resident.
// L1 weights (KS=8, 128 VGPR) live across encoder, reloaded for decoder;
// cell0 JIT-loads per-ks (transient). Cuts per-step L2->CU weight ingest
// 416KB -> 160KB. Base = r14 (1618us): merged A-mix, exp2-tanh, vec h1-save.
// Arithmetic identical to r14.

typedef unsigned short u16;
typedef unsigned int u32;
typedef short bf16x8 __attribute__((ext_vector_type(8)));
typedef float f32x4 __attribute__((ext_vector_type(4)));

// ---- output layout (fp32 elements) ----
#define O_OUT 0
#define O_Z   4194304
#define O_MU  4456448
#define O_LV  4718592
#define O_OLV 4980736

// ---- workspace layout (u16 elements) ----
#define WS_ABF  0          // Ahat bf16 [32][40]
#define WS_PEN0 1280       // packed Wen0 (K=160): nt32*ks5*lane64*8
#define WS_PEN1 83200      // packed Wen1 (K=256)
#define WS_PDE0 214272
#define WS_PDE1 296192
#define WS_PHO  427264     // WhoT  [n][d][h] bf16 (131072)
#define WS_PLV  558336     // WholvT[n][d][h] bf16 (131072)
#define WS_H1   689408     // dec h1 save: [b*63+s][n*128+h] bf16 (16515072)
#define WS_NEED_BYTES 34408960ull

// XN: node-major state [n=32][f], f: 0..31 x | 32..159 h0A | 160..287 h0B |
//     288..415 h1A | 416..543 h1B ; row stride 936 u16 (1872 B, 16B-aligned;
//     552 used + pad keeps LDS >80KB -> 1 block/CU)
#define XSTR 936

__device__ __forceinline__ u16 f2b(float f){
  unsigned x = __float_as_uint(f);
  x += 0x7fffu + ((x>>16)&1u);           // RNE
  return (u16)(x>>16);
}
__device__ __forceinline__ float b2f(u16 u){ return __uint_as_float(((unsigned)u)<<16); }
__device__ __forceinline__ float blo(unsigned u){ return __uint_as_float(u<<16); }
__device__ __forceinline__ float bhi(unsigned u){ return __uint_as_float(u & 0xffff0000u); }

// fast activations (v_rcp/v_exp; branchless)
__device__ __forceinline__ float rcp_(float x){ return __builtin_amdgcn_rcpf(x); }
__device__ __forceinline__ float sigm(float x){ return rcp_(1.f + __expf(-x)); }
__device__ __forceinline__ float tanh_(float x){
  // tanh(x) = 1 - 2/(2^(2*log2e*x)+1); rcp(inf)=0 handles saturation.
  float e = __builtin_amdgcn_exp2f(2.8853900817779268f * x);
  return 1.f - 2.f*rcp_(e + 1.f);
}

// ============ prepack: GCN-normalized adjacency -> bf16 [32][40] ============
__global__ void adj_kernel(const int* __restrict__ ei, u16* __restrict__ ws)
{
  __shared__ float As[1024];
  __shared__ float dinv[32];
  const int tid = threadIdx.x;
  for (int e = tid; e < 1024; e += 256) As[e] = 0.f;
  __syncthreads();
  atomicAdd(&As[ei[256 + tid]*32 + ei[tid]], 1.f);   // A[dst][src] += 1 (E=256)
  __syncthreads();
  if (tid < 32) As[tid*33] += 1.f;                    // +I
  __syncthreads();
  if (tid < 32){
    float s = 0.f;
    for (int j=0;j<32;++j) s += As[tid*32 + j];
    dinv[tid] = rsqrtf(s);
  }
  __syncthreads();
  for (int e = tid; e < 1280; e += 256){
    int i = e / 40, j = e % 40;
    float v = (j < 32) ? As[i*32 + j]*dinv[i]*dinv[j] : 0.f;
    ws[WS_ABF + e] = f2b(v);
  }
}

// ============ prepack: fp32 weights -> bf16 MFMA-B fragment order ============
// packed[((nt*KS+ks)*64+lane)*8 + j] = W[ks*32+(lane>>4)*8+j][nt*16+(lane&15)]
__global__ void pack_kernel(const float* __restrict__ Wen0, const float* __restrict__ Wen1,
                            const float* __restrict__ Wde0, const float* __restrict__ Wde1,
                            const float* __restrict__ Who,  const float* __restrict__ Wholv,
                            u16* __restrict__ ws)
{
  int id = blockIdx.x*256 + threadIdx.x;      // 336*256 = 86016 exactly
  if (id < 53248){
    const float* W; int KS, dstoff, lid;
    if (id < 10240){ W = Wen0; KS = 5; dstoff = WS_PEN0; lid = id; }
    else if (id < 26624){ W = Wen1; KS = 8; dstoff = WS_PEN1; lid = id - 10240; }
    else if (id < 36864){ W = Wde0; KS = 5; dstoff = WS_PDE0; lid = id - 26624; }
    else { W = Wde1; KS = 8; dstoff = WS_PDE1; lid = id - 36864; }
    int l = lid & 63, rest = lid >> 6;
    int ks = rest % KS, nt = rest / KS;
    int n  = nt*16 + (l & 15);
    int k0 = ks*32 + (l >> 4)*8;
    u16 tmp[8];
    #pragma unroll
    for (int j=0;j<8;++j) tmp[j] = f2b(W[(k0 + j)*512 + n]);
    uint4 v;
    v.x = (unsigned)tmp[0] | ((unsigned)tmp[1] << 16);
    v.y = (unsigned)tmp[2] | ((unsigned)tmp[3] << 16);
    v.z = (unsigned)tmp[4] | ((unsigned)tmp[5] << 16);
    v.w = (unsigned)tmp[6] | ((unsigned)tmp[7] << 16);
    *(uint4*)&ws[dstoff + lid*8] = v;
  } else {
    // WT[(n*32+d)*128 + h] = W[(n*128+h)*32 + d], for Who and Wholv
    int e = id - 53248;                        // [0, 32768)
    const float* src = (e < 16384) ? Who : Wholv;
    int dsto = (e < 16384) ? WS_PHO : WS_PLV;
    e &= 16383;
    int n = e >> 9, r = e & 511;
    int d = r >> 4, h0 = (r & 15)*8;
    u16 tmp[8];
    #pragma unroll
    for (int j=0;j<8;++j) tmp[j] = f2b(src[(n*128 + h0 + j)*32 + d]);
    uint4 v;
    v.x = (unsigned)tmp[0] | ((unsigned)tmp[1] << 16);
    v.y = (unsigned)tmp[2] | ((unsigned)tmp[3] << 16);
    v.z = (unsigned)tmp[4] | ((unsigned)tmp[5] << 16);
    v.w = (unsigned)tmp[6] | ((unsigned)tmp[7] << 16);
    *(uint4*)&ws[dsto + (n*4096 + d*128 + h0)] = v;
  }
}

// ============ cell tail: merged A-mix + gates (shared by jit/res cells) ============
__device__ __forceinline__ void cell_tail(
    f32x4 (&acc)[2][4], const float* bias4,
    u16* XN, u16* yt,
    const bf16x8 afr0, const bf16x8 afr1,
    f32x4 (&cst)[2], int hwrite, int l15, int lq, int wave)
{
  // ---- in-wave A-mix (merged): z = Ahat @ Y + b, all 4 gates in one phase ----
  f32x4 acc2[2][4];
  u32* yt32 = (u32*)yt;
  #pragma unroll
  for (int g=0; g<4; ++g){
    #pragma unroll
    for (int mt=0; mt<2; ++mt){
      u32 lo = (u32)f2b(acc[mt][g][0]) | ((u32)f2b(acc[mt][g][1]) << 16);
      u32 hi = (u32)f2b(acc[mt][g][2]) | ((u32)f2b(acc[mt][g][3]) << 16);
      const int base = (g*16 + l15)*20 + mt*8 + lq*2;              // Yt[col][n], u32 idx
      uint2 v; v.x = lo; v.y = hi;
      *(uint2*)&yt32[base] = v;                                    // ds_write_b64
    }
  }
  #pragma unroll
  for (int g=0; g<4; ++g){
    bf16x8 bfr = *(const bf16x8*)&yt[(g*16 + l15)*40 + lq*8];      // B[k=n][col]
    f32x4 vb = {bias4[g], bias4[g], bias4[g], bias4[g]};
    acc2[0][g] = __builtin_amdgcn_mfma_f32_16x16x32_bf16(afr0, bfr, vb, 0, 0, 0);
    acc2[1][g] = __builtin_amdgcn_mfma_f32_16x16x32_bf16(afr1, bfr, vb, 0, 0, 0);
  }
  // ---- gates: c' = sig(f)c + sig(i)tanh(g); h = sig(o)tanh(c') ----
  const int col = wave*16 + l15;
  #pragma unroll
  for (int mt=0;mt<2;++mt){
    #pragma unroll
    for (int q=0;q<4;++q){
      float iv = sigm(acc2[mt][0][q]);
      float fv = sigm(acc2[mt][1][q]);
      float gv = tanh_(acc2[mt][2][q]);
      float ov = sigm(acc2[mt][3][q]);
      float c  = fv*cst[mt][q] + iv*gv;
      cst[mt][q] = c;
      float h  = ov*tanh_(c);
      XN[(mt*16 + lq*4 + q)*XSTR + hwrite + col] = f2b(h);
    }
  }
}

// ============ cell with JIT per-ks weight loads (layer 0, KS=5) ============
template<int KS, int N0>
__device__ __forceinline__ void run_cell_jit(
    const u16* PW, const float* bias4,
    u16* XN, u16* yt,
    const bf16x8 afr0, const bf16x8 afr1,
    f32x4 (&cst)[2], int kb0, int kb1, int hwrite,
    int l15, int lq, int wave)
{
  const bf16x8* PW8 = (const bf16x8*)PW;
  const int lane = lq*16 + l15;
  f32x4 acc[2][4];
  #pragma unroll
  for (int mt=0;mt<2;++mt)
    #pragma unroll
    for (int g=0;g<4;++g){ f32x4 z = {0.f,0.f,0.f,0.f}; acc[mt][g] = z; }
  #pragma unroll
  for (int ks=0; ks<KS; ++ks){
    bf16x8 bw[4];
    #pragma unroll
    for (int g=0; g<4; ++g)
      bw[g] = PW8[((g*8 + wave)*KS + ks)*64 + lane];
    const int off = (ks < N0) ? (kb0 + ks*32) : (kb1 + (ks - N0)*32);
    bf16x8 a0 = *(const bf16x8*)&XN[l15*XSTR + off + lq*8];        // A[m=l15][k]
    bf16x8 a1 = *(const bf16x8*)&XN[(16 + l15)*XSTR + off + lq*8];
    #pragma unroll
    for (int g=0; g<4; ++g){
      acc[0][g] = __builtin_amdgcn_mfma_f32_16x16x32_bf16(a0, bw[g], acc[0][g], 0, 0, 0);
      acc[1][g] = __builtin_amdgcn_mfma_f32_16x16x32_bf16(a1, bw[g], acc[1][g], 0, 0, 0);
    }
  }
  cell_tail(acc, bias4, XN, yt, afr0, afr1, cst, hwrite, l15, lq, wave);
}

// ============ cell with RESIDENT weights (layer 1, KS=8; no loads) ============
template<int KS, int N0>
__device__ __forceinline__ void run_cell_res(
    const bf16x8 (&bw)[8][4], const float* bias4,
    u16* XN, u16* yt,
    const bf16x8 afr0, const bf16x8 afr1,
    f32x4 (&cst)[2], int kb0, int kb1, int hwrite,
    int l15, int lq, int wave)
{
  f32x4 acc[2][4];
  #pragma unroll
  for (int mt=0;mt<2;++mt)
    #pragma unroll
    for (int g=0;g<4;++g){ f32x4 z = {0.f,0.f,0.f,0.f}; acc[mt][g] = z; }
  #pragma unroll
  for (int ks=0; ks<KS; ++ks){
    const int off = (ks < N0) ? (kb0 + ks*32) : (kb1 + (ks - N0)*32);
    bf16x8 a0 = *(const bf16x8*)&XN[l15*XSTR + off + lq*8];        // A[m=l15][k]
    bf16x8 a1 = *(const bf16x8*)&XN[(16 + l15)*XSTR + off + lq*8];
    #pragma unroll
    for (int g=0; g<4; ++g){
      acc[0][g] = __builtin_amdgcn_mfma_f32_16x16x32_bf16(a0, bw[ks][g], acc[0][g], 0, 0, 0);
      acc[1][g] = __builtin_amdgcn_mfma_f32_16x16x32_bf16(a1, bw[ks][g], acc[1][g], 0, 0, 0);
    }
  }
  cell_tail(acc, bias4, XN, yt, afr0, afr1, cst, hwrite, l15, lq, wave);
}

// ============ main persistent kernel: 1 block per batch ============
// NOTE: ws is deliberately NON-const/non-restrict -> weight loads are NOT
// invariant -> cannot be rematerialized across __syncthreads() -> bw1 stays
// register-resident across the loops (the r9-r11 failure mode is closed).
template<bool SAVE>
__global__ __launch_bounds__(512, 2) void lstm_main(
  const float* __restrict__ ts,
  const float* __restrict__ ben0, const float* __restrict__ ben1,
  const float* __restrict__ bde0, const float* __restrict__ bde1,
  const float* __restrict__ Wmu, const float* __restrict__ bmu,
  const float* __restrict__ Wlv, const float* __restrict__ blv,
  const float* __restrict__ bho, const float* __restrict__ bholv,
  const float* __restrict__ Wholv,
  const float* __restrict__ eps,
  u16* ws, u16* __restrict__ wsH1,
  float* __restrict__ dout)
{
  __shared__ __align__(16) u16 XN[32*XSTR];    // 59904 B
  __shared__ __align__(16) u16 Abf[32*40];     //  2560 B
  __shared__ __align__(16) u16 Ytr[8*64*40];   // 40960 B (per-wave 64x40; aliased as zl)
  float* zl = (float*)Ytr;                     // 4096 floats = 16384 B  (phase-ordered)

  const int tid  = threadIdx.x;
  const int lane = tid & 63, wave = tid >> 6;
  const int l15  = lane & 15, lq = lane >> 4;
  const int b    = blockIdx.x;
  u16* yt = Ytr + wave*(64*40);

  for (int e = tid; e < 1280;     e += 512) Abf[e] = ws[WS_ABF + e];
  for (int e = tid; e < 32*XSTR;  e += 512) XN[e] = 0;
  f32x4 c0[2], c1[2];
  {
    f32x4 zz = {0.f,0.f,0.f,0.f};
    c0[0]=c0[1]=c1[0]=c1[1]=zz;
  }
  float biE0[4], biE1[4], biD0[4], biD1[4];
  const int colg = wave*16 + l15;
  #pragma unroll
  for (int g=0; g<4; ++g){
    biE0[g] = ben0[g*128+colg];
    biE1[g] = ben1[g*128+colg];
    biD0[g] = bde0[g*128+colg];
    biD1[g] = bde1[g*128+colg];
  }
  const u16* whoT = ws + WS_PHO;
  const u16* wlvT = ws + WS_PLV;
  const int lane_ = lq*16 + l15;
  // L1 (encoder) weights -> registers BEFORE the loop; ws is non-invariant so
  // these cannot be rematerialized across barriers -> truly resident.
  bf16x8 bw1[8][4];
  {
    const bf16x8* PW8 = (const bf16x8*)(ws + WS_PEN1);
    #pragma unroll
    for (int ks=0; ks<8; ++ks)
      #pragma unroll
      for (int g=0; g<4; ++g)
        bw1[ks][g] = PW8[((g*8 + wave)*8 + ks)*64 + lane_];
  }
  __syncthreads();
  // Ahat MFMA A-fragments: load once, keep in registers
  const bf16x8 afr0 = *(const bf16x8*)&Abf[l15*40 + lq*8];
  const bf16x8 afr1 = *(const bf16x8*)&Abf[(16 + l15)*40 + lq*8];
  // stage x_0 (after zero-fill barrier to avoid write races on x rows)
  {
    const float* xp = ts + (size_t)(b*64)*1024;
    for (int e = tid; e < 1024; e += 512)
      XN[(e >> 5)*XSTR + (e & 31)] = f2b(xp[e]);
  }
  __syncthreads();

  // ---------------- encoder: 2 barriers per step ----------------
  for (int t=0; t<64; ++t){
    const int ph = t & 1;
    run_cell_jit<5,1>(ws+WS_PEN0, biE0, XN, yt, afr0, afr1, c0,
                      0, 32 + 128*ph, 32 + 128*(1-ph), l15, lq, wave);
    __syncthreads();
    // stage x_{t+1} (x rows free: only L0 reads them), overlaps L1 compute
    if (t < 63){
      const float* xp = ts + (size_t)(b*64 + t + 1)*1024;
      for (int e = tid; e < 1024; e += 512)
        XN[(e >> 5)*XSTR + (e & 31)] = f2b(xp[e]);
    }
    run_cell_res<8,4>(bw1, biE1, XN, yt, afr0, afr1, c1,
                      32 + 128*(1-ph), 288 + 128*ph, 288 + 128*(1-ph), l15, lq, wave);
    __syncthreads();
  }
  // final h1 is in bank0 (f=288)

  // ---------------- mu / logvar / zlat ----------------
  for (int k=0;k<8;++k){
    int idx = tid + k*512;
    int n = idx >> 7, o = idx & 127;
    float am = bmu[idx];
    float al = blv[idx];
    for (int h=0; h<128; ++h){
      float hv = b2f(XN[n*XSTR + 288 + h]);
      am += hv * Wmu[(n*128 + h)*128 + o];
      al += hv * Wlv[(n*128 + h)*128 + o];
    }
    float zv = am + eps[b*4096 + idx] * __expf(al);
    zl[idx] = zv;                               // aliases Ytr — phase-ordered
    dout[O_MU + b*4096 + idx] = am;
    dout[O_LV + b*4096 + idx] = al;
    dout[O_Z  + b*4096 + idx] = zv;
  }
  __syncthreads();
  // ---------------- out_last / outlv_last = pnl(zlat, Who/Wholv) ----------------
  #pragma unroll
  for (int k=0;k<2;++k){
    int idx = tid + k*512;
    int n = idx >> 5, d = idx & 31;
    float a  = bho[idx];
    float a2 = bholv[idx];
    const u16* wp = whoT + (idx << 7);          // WhoT[n][d][h] bf16
    for (int h=0; h<128; ++h){
      float hv = zl[n*128 + h];
      a  += hv * b2f(wp[h]);
      a2 += hv * Wholv[(n*128+h)*32 + d];       // fp32 once
    }
    dout[O_OUT + (size_t)(b*64 + 63)*1024 + idx] = a;
    dout[O_OLV + (size_t)(b*64 + 63)*1024 + idx] = a2;
    XN[n*XSTR + d] = f2b(a);                    // decoder feedback x
  }
  // L1 (decoder) weights -> registers, resident across the decoder loop
  {
    const bf16x8* PW8 = (const bf16x8*)(ws + WS_PDE1);
    #pragma unroll
    for (int ks=0; ks<8; ++ks)
      #pragma unroll
      for (int g=0; g<4; ++g)
        bw1[ks][g] = PW8[((g*8 + wave)*8 + ks)*64 + lane_];
  }
  __syncthreads();

  // ---------------- decoder (63 steps, reverse time): 3 barriers per step ----------------
  for (int s=0; s<63; ++s){
    const int pg = s & 1;
    run_cell_jit<5,1>(ws+WS_PDE0, biD0, XN, yt, afr0, afr1, c0,
                      0, 32 + 128*pg, 32 + 128*(1-pg), l15, lq, wave);
    __syncthreads();
    run_cell_res<8,4>(bw1, biD1, XN, yt, afr0, afr1, c1,
                      32 + 128*(1-pg), 288 + 128*pg, 288 + 128*(1-pg), l15, lq, wave);
    __syncthreads();
    const int h1b = 288 + 128*(1-pg);
    if (SAVE){
      // vectorized h1 save: 512 threads x 8 u16 (b128 LDS read + dwordx4 store)
      u16* dst = wsH1 + (size_t)(b*63 + s)*4096;
      int idx = tid*8;
      int n = idx >> 7, h = idx & 127;
      *(uint4*)&dst[idx] = *(const uint4*)&XN[n*XSTR + h1b + h];
    }
    const int tt = 62 - s;
    #pragma unroll
    for (int k=0;k<2;++k){
      int idx = tid + k*512;
      int n = idx >> 5, d = idx & 31;
      float a = bho[idx];
      const u16* wp = whoT + (idx << 7);        // WhoT[n][d][h]
      if (SAVE){
        #pragma unroll 4
        for (int h=0; h<128; h+=8){
          uint4 hv = *(const uint4*)&XN[n*XSTR + h1b + h];
          uint4 wv = *(const uint4*)&wp[h];
          a += blo(hv.x)*blo(wv.x) + bhi(hv.x)*bhi(wv.x);
          a += blo(hv.y)*blo(wv.y) + bhi(hv.y)*bhi(wv.y);
          a += blo(hv.z)*blo(wv.z) + bhi(hv.z)*bhi(wv.z);
          a += blo(hv.w)*blo(wv.w) + bhi(hv.w)*bhi(wv.w);
        }
      } else {
        float a2 = bholv[idx];
        const u16* wp2 = wlvT + (idx << 7);
        #pragma unroll 4
        for (int h=0; h<128; h+=8){
          uint4 hv = *(const uint4*)&XN[n*XSTR + h1b + h];
          uint4 wv = *(const uint4*)&wp[h];
          uint4 w2 = *(const uint4*)&wp2[h];
          float s0=blo(hv.x), s1=bhi(hv.x), s2=blo(hv.y), s3=bhi(hv.y);
          float s4=blo(hv.z), s5=bhi(hv.z), s6=blo(hv.w), s7=bhi(hv.w);
          a  += s0*blo(wv.x) + s1*bhi(wv.x) + s2*blo(wv.y) + s3*bhi(wv.y)
              + s4*blo(wv.z) + s5*bhi(wv.z) + s6*blo(wv.w) + s7*bhi(wv.w);
          a2 += s0*blo(w2.x) + s1*bhi(w2.x) + s2*blo(w2.y) + s3*bhi(w2.y)
              + s4*blo(w2.z) + s5*bhi(w2.z) + s6*blo(w2.w) + s7*bhi(w2.w);
        }
        dout[O_OLV + (size_t)(b*64 + tt)*1024 + idx] = a2;
      }
      dout[O_OUT + (size_t)(b*64 + tt)*1024 + idx] = a;
      XN[n*XSTR + d] = f2b(a);                  // feedback x
    }
    __syncthreads();
  }
}

// ============ epilogue: output_logvar for t<63 (fully parallel, SAVE path) ============
__global__ __launch_bounds__(256) void outlv_kernel(
    const u16* __restrict__ wsH1, const u16* __restrict__ ws,
    const float* __restrict__ bholv, float* __restrict__ dout)
{
  const int n = blockIdx.x, t = blockIdx.y, tid = threadIdx.x;  // t in [0,63)
  __shared__ __align__(16) u16 Ls[64*128];
  const int s = 62 - t;
  for (int e = tid; e < 8192; e += 256){
    int b = e >> 7;
    Ls[e] = wsH1[(size_t)(b*63 + s)*4096 + n*128 + (e & 127)];
  }
  __syncthreads();
  const int d = tid & 31, bq = tid >> 5;
  const u16* wp2 = ws + WS_PLV + ((n*32 + d) << 7);   // WholvT[n][d][h]
  const float bias = bholv[n*32 + d];
  for (int b = bq; b < 64; b += 8){
    float acc = bias;
    #pragma unroll 4
    for (int h = 0; h < 128; h += 8){
      uint4 sv = *(const uint4*)&Ls[b*128 + h];
      uint4 wv = *(const uint4*)&wp2[h];
      acc += blo(sv.x)*blo(wv.x) + bhi(sv.x)*bhi(wv.x);
      acc += blo(sv.y)*blo(wv.y) + bhi(sv.y)*bhi(wv.y);
      acc += blo(sv.z)*blo(wv.z) + bhi(sv.z)*bhi(wv.z);
      acc += blo(sv.w)*blo(wv.w) + bhi(sv.w)*bhi(wv.w);
    }
    dout[O_OLV + (size_t)(b*64 + t)*1024 + n*32 + d] = acc;
  }
}

extern "C" void kernel_launch(void* const* d_in, const int* in_sizes, int n_in,
                              void* d_out, int out_size, void* d_ws, size_t ws_size,
                              hipStream_t stream)
{
  (void)in_sizes; (void)n_in; (void)out_size;
  const float* ts   = (const float*)d_in[0];
  const int*   ei   = (const int*)d_in[1];
  const float* Wen0 = (const float*)d_in[2];
  const float* ben0 = (const float*)d_in[3];
  const float* Wen1 = (const float*)d_in[4];
  const float* ben1 = (const float*)d_in[5];
  const float* Wde0 = (const float*)d_in[6];
  const float* bde0 = (const float*)d_in[7];
  const float* Wde1 = (const float*)d_in[8];
  const float* bde1 = (const float*)d_in[9];
  const float* Wmu  = (const float*)d_in[10];
  const float* bmu  = (const float*)d_in[11];
  const float* Wlv  = (const float*)d_in[12];
  const float* blv  = (const float*)d_in[13];
  const float* Who  = (const float*)d_in[14];
  const float* bho  = (const float*)d_in[15];
  const float* Wholv= (const float*)d_in[16];
  const float* bholv= (const float*)d_in[17];
  const float* eps  = (const float*)d_in[18];
  u16*   ws   = (u16*)d_ws;
  float* dout = (float*)d_out;
  const bool save = ws_size >= WS_NEED_BYTES;

  adj_kernel<<<1, 256, 0, stream>>>(ei, ws);
  pack_kernel<<<336, 256, 0, stream>>>(Wen0, Wen1, Wde0, Wde1, Who, Wholv, ws);
  if (save){
    lstm_main<true><<<64, 512, 0, stream>>>(ts, ben0, ben1, bde0, bde1, Wmu, bmu, Wlv, blv,
        bho, bholv, Wholv, eps, ws, ws + WS_H1, dout);
    outlv_kernel<<<dim3(32,63), 256, 0, stream>>>(ws + WS_H1, ws, bholv, dout);
  } else {
    lstm_main<false><<<64, 512, 0, stream>>>(ts, ben0, ben1, bde0, bde1, Wmu, bmu, Wlv, blv,
        bho, bholv, Wholv, eps, ws, ws, dout);
  }
}

// Round 12
// 1762.599 us; speedup vs baseline: 1.0334x; 1.0334x over previous
//
#include <hip/hip_runtime.h>

// GraphLSTM-VAE on MI355X — round 16: encoder barrier fusion (2/step -> 1/step).
// r15 post-mortem: residency arc dead (5 attempts, 3 mechanisms; IPA re-derives
// invariance since ws is never written). Revised model: weight ingest ~2kcyc/step
// (64 active CUs -> 4x L2 share); step time is barrier-serialized latency chains.
// Change vs r14 (1618us): dual x banks (f=0 / f=544) let cell1(t) and cell0(t+1)
// touch disjoint LDS -> the barrier between them is REMOVED. Fast waves flow from
// cell1(t) into cell0(t+1), overlapping the two cells' stall chains (r13's goal
// without the VGPR collapse). x staging joins the cell0 phase, early-issue/
// write-late. Decoder unchanged (3 true deps). Arithmetic identical to r14.
// Bank proof: cell1(t): R h0[1-ph], h1[ph]; W h1[1-ph]. cell0(t+1): R x[1-ph],
// h0[1-ph](read-read); W h0[ph]; stage x->bank ph (no concurrent reader).

typedef unsigned short u16;
typedef unsigned int u32;
typedef short bf16x8 __attribute__((ext_vector_type(8)));
typedef float f32x4 __attribute__((ext_vector_type(4)));

// ---- output layout (fp32 elements) ----
#define O_OUT 0
#define O_Z   4194304
#define O_MU  4456448
#define O_LV  4718592
#define O_OLV 4980736

// ---- workspace layout (u16 elements) ----
#define WS_ABF  0          // Ahat bf16 [32][40]
#define WS_PEN0 1280       // packed Wen0 (K=160): nt32*ks5*lane64*8
#define WS_PEN1 83200      // packed Wen1 (K=256)
#define WS_PDE0 214272
#define WS_PDE1 296192
#define WS_PHO  427264     // WhoT  [n][d][h] bf16 (131072)
#define WS_PLV  558336     // WholvT[n][d][h] bf16 (131072)
#define WS_H1   689408     // dec h1 save: [b*63+s][n*128+h] bf16 (16515072)
#define WS_NEED_BYTES 34408960ull

// XN: node-major state [n=32][f], row stride 936 u16 (1872 B, 16B-aligned).
// f: 0..31 xA | 32..159 h0A | 160..287 h0B | 288..415 h1A | 416..543 h1B |
//    544..575 xB | rest pad (keeps LDS >80KB -> 1 block/CU)
#define XSTR 936

__device__ __forceinline__ u16 f2b(float f){
  unsigned x = __float_as_uint(f);
  x += 0x7fffu + ((x>>16)&1u);           // RNE
  return (u16)(x>>16);
}
__device__ __forceinline__ float b2f(u16 u){ return __uint_as_float(((unsigned)u)<<16); }
__device__ __forceinline__ float blo(unsigned u){ return __uint_as_float(u<<16); }
__device__ __forceinline__ float bhi(unsigned u){ return __uint_as_float(u & 0xffff0000u); }

// fast activations (v_rcp/v_exp; branchless)
__device__ __forceinline__ float rcp_(float x){ return __builtin_amdgcn_rcpf(x); }
__device__ __forceinline__ float sigm(float x){ return rcp_(1.f + __expf(-x)); }
__device__ __forceinline__ float tanh_(float x){
  // tanh(x) = 1 - 2/(2^(2*log2e*x)+1); rcp(inf)=0 handles saturation.
  float e = __builtin_amdgcn_exp2f(2.8853900817779268f * x);
  return 1.f - 2.f*rcp_(e + 1.f);
}

// ============ prepack: GCN-normalized adjacency -> bf16 [32][40] ============
__global__ void adj_kernel(const int* __restrict__ ei, u16* __restrict__ ws)
{
  __shared__ float As[1024];
  __shared__ float dinv[32];
  const int tid = threadIdx.x;
  for (int e = tid; e < 1024; e += 256) As[e] = 0.f;
  __syncthreads();
  atomicAdd(&As[ei[256 + tid]*32 + ei[tid]], 1.f);   // A[dst][src] += 1 (E=256)
  __syncthreads();
  if (tid < 32) As[tid*33] += 1.f;                    // +I
  __syncthreads();
  if (tid < 32){
    float s = 0.f;
    for (int j=0;j<32;++j) s += As[tid*32 + j];
    dinv[tid] = rsqrtf(s);
  }
  __syncthreads();
  for (int e = tid; e < 1280; e += 256){
    int i = e / 40, j = e % 40;
    float v = (j < 32) ? As[i*32 + j]*dinv[i]*dinv[j] : 0.f;
    ws[WS_ABF + e] = f2b(v);
  }
}

// ============ prepack: fp32 weights -> bf16 MFMA-B fragment order ============
// packed[((nt*KS+ks)*64+lane)*8 + j] = W[ks*32+(lane>>4)*8+j][nt*16+(lane&15)]
__global__ void pack_kernel(const float* __restrict__ Wen0, const float* __restrict__ Wen1,
                            const float* __restrict__ Wde0, const float* __restrict__ Wde1,
                            const float* __restrict__ Who,  const float* __restrict__ Wholv,
                            u16* __restrict__ ws)
{
  int id = blockIdx.x*256 + threadIdx.x;      // 336*256 = 86016 exactly
  if (id < 53248){
    const float* W; int KS, dstoff, lid;
    if (id < 10240){ W = Wen0; KS = 5; dstoff = WS_PEN0; lid = id; }
    else if (id < 26624){ W = Wen1; KS = 8; dstoff = WS_PEN1; lid = id - 10240; }
    else if (id < 36864){ W = Wde0; KS = 5; dstoff = WS_PDE0; lid = id - 26624; }
    else { W = Wde1; KS = 8; dstoff = WS_PDE1; lid = id - 36864; }
    int l = lid & 63, rest = lid >> 6;
    int ks = rest % KS, nt = rest / KS;
    int n  = nt*16 + (l & 15);
    int k0 = ks*32 + (l >> 4)*8;
    u16 tmp[8];
    #pragma unroll
    for (int j=0;j<8;++j) tmp[j] = f2b(W[(k0 + j)*512 + n]);
    uint4 v;
    v.x = (unsigned)tmp[0] | ((unsigned)tmp[1] << 16);
    v.y = (unsigned)tmp[2] | ((unsigned)tmp[3] << 16);
    v.z = (unsigned)tmp[4] | ((unsigned)tmp[5] << 16);
    v.w = (unsigned)tmp[6] | ((unsigned)tmp[7] << 16);
    *(uint4*)&ws[dstoff + lid*8] = v;
  } else {
    // WT[(n*32+d)*128 + h] = W[(n*128+h)*32 + d], for Who and Wholv
    int e = id - 53248;                        // [0, 32768)
    const float* src = (e < 16384) ? Who : Wholv;
    int dsto = (e < 16384) ? WS_PHO : WS_PLV;
    e &= 16383;
    int n = e >> 9, r = e & 511;
    int d = r >> 4, h0 = (r & 15)*8;
    u16 tmp[8];
    #pragma unroll
    for (int j=0;j<8;++j) tmp[j] = f2b(src[(n*128 + h0 + j)*32 + d]);
    uint4 v;
    v.x = (unsigned)tmp[0] | ((unsigned)tmp[1] << 16);
    v.y = (unsigned)tmp[2] | ((unsigned)tmp[3] << 16);
    v.z = (unsigned)tmp[4] | ((unsigned)tmp[5] << 16);
    v.w = (unsigned)tmp[6] | ((unsigned)tmp[7] << 16);
    *(uint4*)&ws[dsto + (n*4096 + d*128 + h0)] = v;
  }
}

// ============ one GCN-LSTM cell: Y=xh@W (MFMA) -> in-wave A-mix -> gates ============
// K region 0: N0 blocks at kb0; region 1: (KS-N0) blocks at kb1.
// yt: this wave's private 64x40-u16 LDS scratch (ALL 64 Y cols at once).
template<int KS, int N0>
__device__ __forceinline__ void run_cell(
    const u16* __restrict__ PW, const float* bias4,
    u16* XN, u16* yt,
    const bf16x8 afr0, const bf16x8 afr1,
    f32x4 (&cst)[2], int kb0, int kb1, int hwrite,
    int l15, int lq, int wave)
{
  const bf16x8* PW8 = (const bf16x8*)PW;
  const int lane = lq*16 + l15;
  // ---- burst-load ALL weight B-fragments (KS*4 x 16B per lane) ----
  bf16x8 bw[KS][4];
  #pragma unroll
  for (int ks=0; ks<KS; ++ks){
    #pragma unroll
    for (int g=0; g<4; ++g)
      bw[ks][g] = PW8[((g*8 + wave)*KS + ks)*64 + lane];
  }
  // ---- Y = xh @ W : per wave cols {g*128 + wave*16 + l15} ----
  f32x4 acc[2][4];
  #pragma unroll
  for (int mt=0;mt<2;++mt)
    #pragma unroll
    for (int g=0;g<4;++g){ f32x4 z = {0.f,0.f,0.f,0.f}; acc[mt][g] = z; }
  #pragma unroll
  for (int ks=0; ks<KS; ++ks){
    const int off = (ks < N0) ? (kb0 + ks*32) : (kb1 + (ks - N0)*32);
    bf16x8 a0 = *(const bf16x8*)&XN[l15*XSTR + off + lq*8];        // A[m=l15][k]
    bf16x8 a1 = *(const bf16x8*)&XN[(16 + l15)*XSTR + off + lq*8];
    #pragma unroll
    for (int g=0; g<4; ++g){
      acc[0][g] = __builtin_amdgcn_mfma_f32_16x16x32_bf16(a0, bw[ks][g], acc[0][g], 0, 0, 0);
      acc[1][g] = __builtin_amdgcn_mfma_f32_16x16x32_bf16(a1, bw[ks][g], acc[1][g], 0, 0, 0);
    }
  }
  // ---- in-wave A-mix (merged): z = Ahat @ Y + b, all 4 gates in one phase ----
  f32x4 acc2[2][4];
  u32* yt32 = (u32*)yt;
  #pragma unroll
  for (int g=0; g<4; ++g){
    #pragma unroll
    for (int mt=0; mt<2; ++mt){
      u32 lo = (u32)f2b(acc[mt][g][0]) | ((u32)f2b(acc[mt][g][1]) << 16);
      u32 hi = (u32)f2b(acc[mt][g][2]) | ((u32)f2b(acc[mt][g][3]) << 16);
      const int base = (g*16 + l15)*20 + mt*8 + lq*2;              // Yt[col][n], u32 idx
      uint2 v; v.x = lo; v.y = hi;
      *(uint2*)&yt32[base] = v;                                    // ds_write_b64
    }
  }
  #pragma unroll
  for (int g=0; g<4; ++g){
    bf16x8 bfr = *(const bf16x8*)&yt[(g*16 + l15)*40 + lq*8];      // B[k=n][col]
    f32x4 vb = {bias4[g], bias4[g], bias4[g], bias4[g]};
    acc2[0][g] = __builtin_amdgcn_mfma_f32_16x16x32_bf16(afr0, bfr, vb, 0, 0, 0);
    acc2[1][g] = __builtin_amdgcn_mfma_f32_16x16x32_bf16(afr1, bfr, vb, 0, 0, 0);
  }
  // ---- gates: c' = sig(f)c + sig(i)tanh(g); h = sig(o)tanh(c') ----
  const int col = wave*16 + l15;
  #pragma unroll
  for (int mt=0;mt<2;++mt){
    #pragma unroll
    for (int q=0;q<4;++q){
      float iv = sigm(acc2[mt][0][q]);
      float fv = sigm(acc2[mt][1][q]);
      float gv = tanh_(acc2[mt][2][q]);
      float ov = sigm(acc2[mt][3][q]);
      float c  = fv*cst[mt][q] + iv*gv;
      cst[mt][q] = c;
      float h  = ov*tanh_(c);
      XN[(mt*16 + lq*4 + q)*XSTR + hwrite + col] = f2b(h);
    }
  }
}

// ============ main persistent kernel: 1 block per batch ============
template<bool SAVE>
__global__ __launch_bounds__(512, 2) void lstm_main(
  const float* __restrict__ ts,
  const float* __restrict__ ben0, const float* __restrict__ ben1,
  const float* __restrict__ bde0, const float* __restrict__ bde1,
  const float* __restrict__ Wmu, const float* __restrict__ bmu,
  const float* __restrict__ Wlv, const float* __restrict__ blv,
  const float* __restrict__ bho, const float* __restrict__ bholv,
  const float* __restrict__ Wholv,
  const float* __restrict__ eps,
  const u16* __restrict__ ws, u16* __restrict__ wsH1,
  float* __restrict__ dout)
{
  __shared__ __align__(16) u16 XN[32*XSTR];    // 59904 B
  __shared__ __align__(16) u16 Abf[32*40];     //  2560 B
  __shared__ __align__(16) u16 Ytr[8*64*40];   // 40960 B (per-wave 64x40; aliased as zl)
  float* zl = (float*)Ytr;                     // 4096 floats = 16384 B  (phase-ordered)

  const int tid  = threadIdx.x;
  const int lane = tid & 63, wave = tid >> 6;
  const int l15  = lane & 15, lq = lane >> 4;
  const int b    = blockIdx.x;
  u16* yt = Ytr + wave*(64*40);

  for (int e = tid; e < 1280;     e += 512) Abf[e] = ws[WS_ABF + e];
  for (int e = tid; e < 32*XSTR;  e += 512) XN[e] = 0;
  f32x4 c0[2], c1[2];
  {
    f32x4 zz = {0.f,0.f,0.f,0.f};
    c0[0]=c0[1]=c1[0]=c1[1]=zz;
  }
  float biE0[4], biE1[4], biD0[4], biD1[4];
  const int colg = wave*16 + l15;
  #pragma unroll
  for (int g=0; g<4; ++g){
    biE0[g] = ben0[g*128+colg];
    biE1[g] = ben1[g*128+colg];
    biD0[g] = bde0[g*128+colg];
    biD1[g] = bde1[g*128+colg];
  }
  const u16* whoT = ws + WS_PHO;
  const u16* wlvT = ws + WS_PLV;
  __syncthreads();
  // Ahat MFMA A-fragments: load once, keep in registers
  const bf16x8 afr0 = *(const bf16x8*)&Abf[l15*40 + lq*8];
  const bf16x8 afr1 = *(const bf16x8*)&Abf[(16 + l15)*40 + lq*8];
  // stage x_0 into bank0 (after zero-fill barrier)
  {
    const float* xp = ts + (size_t)(b*64)*1024;
    for (int e = tid; e < 1024; e += 512)
      XN[(e >> 5)*XSTR + (e & 31)] = f2b(xp[e]);
  }
  __syncthreads();

  // ---------------- encoder: ONE barrier per step (fused cell1|cell0) --------
  // x(t) lives in bank (t&1): bank0 @ f=0, bank1 @ f=544.
  // Phase P1(t): cell0(t) [R x[ph],h0[ph]; W h0[1-ph]] + stage x(t+1)->bank 1-ph
  //   (early-issue loads, write-late). BARRIER.
  // Phase P2(t): cell1(t) [R h0[1-ph],h1[ph]; W h1[1-ph]] — then flows straight
  //   into P1(t+1): R x[1-ph] (staged pre-bar), h0[1-ph] (read-read w/ cell1);
  //   W h0[ph] (untouched by cell1); stage->bank ph (no concurrent reader).
  for (int t=0; t<64; ++t){
    const int ph = t & 1;
    float xv0, xv1;
    if (t < 63){
      const float* xp = ts + (size_t)(b*64 + t + 1)*1024;
      xv0 = xp[tid]; xv1 = xp[tid + 512];
    }
    run_cell<5,1>(ws+WS_PEN0, biE0, XN, yt, afr0, afr1, c0,
                  ph ? 544 : 0, 32 + 128*ph, 32 + 128*(1-ph), l15, lq, wave);
    if (t < 63){
      const int xb = ph ? 0 : 544;             // bank (1-ph)
      XN[(tid >> 5)*XSTR + xb + (tid & 31)] = f2b(xv0);
      XN[((tid + 512) >> 5)*XSTR + xb + ((tid + 512) & 31)] = f2b(xv1);
    }
    __syncthreads();
    run_cell<8,4>(ws+WS_PEN1, biE1, XN, yt, afr0, afr1, c1,
                  32 + 128*(1-ph), 288 + 128*ph, 288 + 128*(1-ph), l15, lq, wave);
    // no barrier — fused with next step's cell0 (bank-disjoint, see proof above)
  }
  __syncthreads();
  // final h1 is in bank0 (f=288); final h0 in bank0 (f=32)

  // ---------------- mu / logvar / zlat ----------------
  for (int k=0;k<8;++k){
    int idx = tid + k*512;
    int n = idx >> 7, o = idx & 127;
    float am = bmu[idx];
    float al = blv[idx];
    for (int h=0; h<128; ++h){
      float hv = b2f(XN[n*XSTR + 288 + h]);
      am += hv * Wmu[(n*128 + h)*128 + o];
      al += hv * Wlv[(n*128 + h)*128 + o];
    }
    float zv = am + eps[b*4096 + idx] * __expf(al);
    zl[idx] = zv;                               // aliases Ytr — phase-ordered
    dout[O_MU + b*4096 + idx] = am;
    dout[O_LV + b*4096 + idx] = al;
    dout[O_Z  + b*4096 + idx] = zv;
  }
  __syncthreads();
  // ---------------- out_last / outlv_last = pnl(zlat, Who/Wholv) ----------------
  #pragma unroll
  for (int k=0;k<2;++k){
    int idx = tid + k*512;
    int n = idx >> 5, d = idx & 31;
    float a  = bho[idx];
    float a2 = bholv[idx];
    const u16* wp = whoT + (idx << 7);          // WhoT[n][d][h] bf16
    for (int h=0; h<128; ++h){
      float hv = zl[n*128 + h];
      a  += hv * b2f(wp[h]);
      a2 += hv * Wholv[(n*128+h)*32 + d];       // fp32 once
    }
    dout[O_OUT + (size_t)(b*64 + 63)*1024 + idx] = a;
    dout[O_OLV + (size_t)(b*64 + 63)*1024 + idx] = a2;
    XN[n*XSTR + d] = f2b(a);                    // decoder feedback x (bank0)
  }
  __syncthreads();

  // ---------------- decoder (63 steps, reverse time): 3 barriers per step ----------------
  for (int s=0; s<63; ++s){
    const int pg = s & 1;
    run_cell<5,1>(ws+WS_PDE0, biD0, XN, yt, afr0, afr1, c0,
                  0, 32 + 128*pg, 32 + 128*(1-pg), l15, lq, wave);
    __syncthreads();
    run_cell<8,4>(ws+WS_PDE1, biD1, XN, yt, afr0, afr1, c1,
                  32 + 128*(1-pg), 288 + 128*pg, 288 + 128*(1-pg), l15, lq, wave);
    __syncthreads();
    const int h1b = 288 + 128*(1-pg);
    if (SAVE){
      // vectorized h1 save: 512 threads x 8 u16 (b128 LDS read + dwordx4 store)
      u16* dst = wsH1 + (size_t)(b*63 + s)*4096;
      int idx = tid*8;
      int n = idx >> 7, h = idx & 127;
      *(uint4*)&dst[idx] = *(const uint4*)&XN[n*XSTR + h1b + h];
    }
    const int tt = 62 - s;
    #pragma unroll
    for (int k=0;k<2;++k){
      int idx = tid + k*512;
      int n = idx >> 5, d = idx & 31;
      float a = bho[idx];
      const u16* wp = whoT + (idx << 7);        // WhoT[n][d][h]
      if (SAVE){
        #pragma unroll 4
        for (int h=0; h<128; h+=8){
          uint4 hv = *(const uint4*)&XN[n*XSTR + h1b + h];
          uint4 wv = *(const uint4*)&wp[h];
          a += blo(hv.x)*blo(wv.x) + bhi(hv.x)*bhi(wv.x);
          a += blo(hv.y)*blo(wv.y) + bhi(hv.y)*bhi(wv.y);
          a += blo(hv.z)*blo(wv.z) + bhi(hv.z)*bhi(wv.z);
          a += blo(hv.w)*blo(wv.w) + bhi(hv.w)*bhi(wv.w);
        }
      } else {
        float a2 = bholv[idx];
        const u16* wp2 = wlvT + (idx << 7);
        #pragma unroll 4
        for (int h=0; h<128; h+=8){
          uint4 hv = *(const uint4*)&XN[n*XSTR + h1b + h];
          uint4 wv = *(const uint4*)&wp[h];
          uint4 w2 = *(const uint4*)&wp2[h];
          float s0=blo(hv.x), s1=bhi(hv.x), s2=blo(hv.y), s3=bhi(hv.y);
          float s4=blo(hv.z), s5=bhi(hv.z), s6=blo(hv.w), s7=bhi(hv.w);
          a  += s0*blo(wv.x) + s1*bhi(wv.x) + s2*blo(wv.y) + s3*bhi(wv.y)
              + s4*blo(wv.z) + s5*bhi(wv.z) + s6*blo(wv.w) + s7*bhi(wv.w);
          a2 += s0*blo(w2.x) + s1*bhi(w2.x) + s2*blo(w2.y) + s3*bhi(w2.y)
              + s4*blo(w2.z) + s5*bhi(w2.z) + s6*blo(w2.w) + s7*bhi(w2.w);
        }
        dout[O_OLV + (size_t)(b*64 + tt)*1024 + idx] = a2;
      }
      dout[O_OUT + (size_t)(b*64 + tt)*1024 + idx] = a;
      XN[n*XSTR + d] = f2b(a);                  // feedback x (bank0)
    }
    __syncthreads();
  }
}

// ============ epilogue: output_logvar for t<63 (fully parallel, SAVE path) ============
__global__ __launch_bounds__(256) void outlv_kernel(
    const u16* __restrict__ wsH1, const u16* __restrict__ ws,
    const float* __restrict__ bholv, float* __restrict__ dout)
{
  const int n = blockIdx.x, t = blockIdx.y, tid = threadIdx.x;  // t in [0,63)
  __shared__ __align__(16) u16 Ls[64*128];
  const int s = 62 - t;
  for (int e = tid; e < 8192; e += 256){
    int b = e >> 7;
    Ls[e] = wsH1[(size_t)(b*63 + s)*4096 + n*128 + (e & 127)];
  }
  __syncthreads();
  const int d = tid & 31, bq = tid >> 5;
  const u16* wp2 = ws + WS_PLV + ((n*32 + d) << 7);   // WholvT[n][d][h]
  const float bias = bholv[n*32 + d];
  for (int b = bq; b < 64; b += 8){
    float acc = bias;
    #pragma unroll 4
    for (int h = 0; h < 128; h += 8){
      uint4 sv = *(const uint4*)&Ls[b*128 + h];
      uint4 wv = *(const uint4*)&wp2[h];
      acc += blo(sv.x)*blo(wv.x) + bhi(sv.x)*bhi(wv.x);
      acc += blo(sv.y)*blo(wv.y) + bhi(sv.y)*bhi(wv.y);
      acc += blo(sv.z)*blo(wv.z) + bhi(sv.z)*bhi(wv.z);
      acc += blo(sv.w)*blo(wv.w) + bhi(sv.w)*bhi(wv.w);
    }
    dout[O_OLV + (size_t)(b*64 + t)*1024 + n*32 + d] = acc;
  }
}

extern "C" void kernel_launch(void* const* d_in, const int* in_sizes, int n_in,
                              void* d_out, int out_size, void* d_ws, size_t ws_size,
                              hipStream_t stream)
{
  (void)in_sizes; (void)n_in; (void)out_size;
  const float* ts   = (const float*)d_in[0];
  const int*   ei   = (const int*)d_in[1];
  const float* Wen0 = (const float*)d_in[2];
  const float* ben0 = (const float*)d_in[3];
  const float* Wen1 = (const float*)d_in[4];
  const float* ben1 = (const float*)d_in[5];
  const float* Wde0 = (const float*)d_in[6];
  const float* bde0 = (const float*)d_in[7];
  const float* Wde1 = (const float*)d_in[8];
  const float* bde1 = (const float*)d_in[9];
  const float* Wmu  = (const float*)d_in[10];
  const float* bmu  = (const float*)d_in[11];
  const float* Wlv  = (const float*)d_in[12];
  const float* blv  = (const float*)d_in[13];
  const float* Who  = (const float*)d_in[14];
  const float* bho  = (const float*)d_in[15];
  const float* Wholv= (const float*)d_in[16];
  const float* bholv= (const float*)d_in[17];
  const float* eps  = (const float*)d_in[18];
  u16*   ws   = (u16*)d_ws;
  float* dout = (float*)d_out;
  const bool save = ws_size >= WS_NEED_BYTES;

  adj_kernel<<<1, 256, 0, stream>>>(ei, ws);
  pack_kernel<<<336, 256, 0, stream>>>(Wen0, Wen1, Wde0, Wde1, Who, Wholv, ws);
  if (save){
    lstm_main<true><<<64, 512, 0, stream>>>(ts, ben0, ben1, bde0, bde1, Wmu, bmu, Wlv, blv,
        bho, bholv, Wholv, eps, ws, ws + WS_H1, dout);
    outlv_kernel<<<dim3(32,63), 256, 0, stream>>>(ws + WS_H1, ws, bholv, dout);
  } else {
    lstm_main<false><<<64, 512, 0, stream>>>(ts, ben0, ben1, bde0, bde1, Wmu, bmu, Wlv, blv,
        bho, bholv, Wholv, eps, ws, ws, dout);
  }
}